// Round 2
// baseline (54.101 us; speedup 1.0000x reference)
//
#include <hip/hip_runtime.h>

#define SCALE 0.25f
#define OUT_H 7
#define OUT_W 7
#define CV 256
#define HV 200
#define WV 200

__global__ __launch_bounds__(256) void roi_align_kernel(
    const float* __restrict__ fm, const float* __restrict__ rois,
    float* __restrict__ out)
{
    __shared__ int s_b;
    __shared__ int s_x0[OUT_W], s_x1[OUT_W], s_y0[OUT_H], s_y1[OUT_H];
    __shared__ float s_wx0[OUT_W], s_wx1[OUT_W], s_wy0[OUT_H], s_wy1[OUT_H];

    const int n = blockIdx.x;
    const int tid = threadIdx.x;

    if (tid < OUT_W) {
        const float r0 = rois[n * 5 + 0] * SCALE;
        const float r1 = rois[n * 5 + 1] * SCALE;
        const float r2 = rois[n * 5 + 2] * SCALE;
        const float r3 = rois[n * 5 + 3] * SCALE;
        const float r4 = rois[n * 5 + 4] * SCALE;
        if (tid == 0) s_b = (int)r4;  // faithful: int(batch_idx * scale)

        // second scale application (faithful quirk)
        const float c0 = r0 * SCALE, c1 = r1 * SCALE;
        const float c2 = r2 * SCALE, c3 = r3 * SCALE;

        const float x_min = fminf(fmaxf(c0, 0.0f), (float)(WV - 1));
        const float y_min = fminf(fmaxf(c1, 0.0f), (float)(HV - 1));
        const float x_max = fminf(fmaxf(c2, x_min + 1.0f), (float)WV);
        const float y_max = fminf(fmaxf(c3, y_min + 1.0f), (float)HV);

        const float sx = x_max - x_min, tx = 2.0f * x_min / (float)WV - 1.0f;
        const float sy = y_max - y_min, ty = 2.0f * y_min / (float)HV - 1.0f;

        // x-dimension table for j = tid
        {
            const float xs = (2.0f * (float)tid + 1.0f) / (float)OUT_W - 1.0f;
            const float gx = sx * xs + tx;
            const float px = ((gx + 1.0f) * (float)WV - 1.0f) * 0.5f;
            const float x0f = floorf(px);
            const float w1 = px - x0f, w0 = 1.0f - w1;
            const int x0i = (int)x0f, x1i = x0i + 1;
            const float v0 = (x0i >= 0 && x0i < WV) ? 1.0f : 0.0f;
            const float v1 = (x1i >= 0 && x1i < WV) ? 1.0f : 0.0f;
            s_x0[tid] = min(max(x0i, 0), WV - 1);
            s_x1[tid] = min(max(x1i, 0), WV - 1);
            s_wx0[tid] = w0 * v0;
            s_wx1[tid] = w1 * v1;
        }
        // y-dimension table for i = tid
        {
            const float ys = (2.0f * (float)tid + 1.0f) / (float)OUT_H - 1.0f;
            const float gy = sy * ys + ty;
            const float py = ((gy + 1.0f) * (float)HV - 1.0f) * 0.5f;
            const float y0f = floorf(py);
            const float w1 = py - y0f, w0 = 1.0f - w1;
            const int y0i = (int)y0f, y1i = y0i + 1;
            const float v0 = (y0i >= 0 && y0i < HV) ? 1.0f : 0.0f;
            const float v1 = (y1i >= 0 && y1i < HV) ? 1.0f : 0.0f;
            s_y0[tid] = min(max(y0i, 0), HV - 1);
            s_y1[tid] = min(max(y1i, 0), HV - 1);
            s_wy0[tid] = w0 * v0;
            s_wy1[tid] = w1 * v1;
        }
    }
    __syncthreads();

    const int b = s_b;
    const float* __restrict__ fmb = fm + (size_t)b * CV * HV * WV;
    float* __restrict__ outn = out + (size_t)n * CV * OUT_H * OUT_W;

    for (int e = tid; e < CV * OUT_H * OUT_W; e += 256) {
        const int c = e / 49;
        const int p = e - c * 49;
        const int oh = p / 7;
        const int ow = p - oh * 7;
        const float* __restrict__ base = fmb + (size_t)c * (HV * WV);
        const float* __restrict__ row0 = base + s_y0[oh] * WV;
        const float* __restrict__ row1 = base + s_y1[oh] * WV;
        const float a00 = row0[s_x0[ow]];
        const float a01 = row0[s_x1[ow]];
        const float a10 = row1[s_x0[ow]];
        const float a11 = row1[s_x1[ow]];
        const float v = s_wy0[oh] * (s_wx0[ow] * a00 + s_wx1[ow] * a01)
                      + s_wy1[oh] * (s_wx0[ow] * a10 + s_wx1[ow] * a11);
        outn[e] = v;
    }
}

extern "C" void kernel_launch(void* const* d_in, const int* in_sizes, int n_in,
                              void* d_out, int out_size, void* d_ws, size_t ws_size,
                              hipStream_t stream) {
    const float* fm = (const float*)d_in[0];
    const float* rois = (const float*)d_in[1];
    float* out = (float*)d_out;
    const int N = in_sizes[1] / 5;  // 1000 rois
    roi_align_kernel<<<dim3(N), dim3(256), 0, stream>>>(fm, rois, out);
}

// Round 3
// 49.029 us; speedup vs baseline: 1.1034x; 1.1034x over previous
//
#include <hip/hip_runtime.h>

#define SCALE 0.25f
#define OUT_H 7
#define OUT_W 7
#define CV 256
#define HV 200
#define WV 200
#define CPB 64              // channels per block (CV / gridDim.y, gridDim.y = 4)
#define EPB (CPB * 49)      // elements per block = 3136

__global__ __launch_bounds__(256) void roi_align_kernel(
    const float* __restrict__ fm, const float* __restrict__ rois,
    float* __restrict__ out)
{
    __shared__ int s_b;
    __shared__ int   s_o00[49], s_o01[49], s_o10[49], s_o11[49];
    __shared__ float s_w00[49], s_w01[49], s_w10[49], s_w11[49];

    const int n = blockIdx.x;
    const int q = blockIdx.y;           // channel quarter 0..3
    const int tid = threadIdx.x;

    if (tid < 49) {
        // every one of the 49 setup threads redundantly computes the roi scalars (cheap)
        const float r0 = rois[n * 5 + 0] * SCALE;
        const float r1 = rois[n * 5 + 1] * SCALE;
        const float r2 = rois[n * 5 + 2] * SCALE;
        const float r3 = rois[n * 5 + 3] * SCALE;
        if (tid == 0) s_b = (int)(rois[n * 5 + 4] * SCALE);  // faithful quirk

        const float c0 = r0 * SCALE, c1 = r1 * SCALE;        // second scale (faithful)
        const float c2 = r2 * SCALE, c3 = r3 * SCALE;

        const float x_min = fminf(fmaxf(c0, 0.0f), (float)(WV - 1));
        const float y_min = fminf(fmaxf(c1, 0.0f), (float)(HV - 1));
        const float x_max = fminf(fmaxf(c2, x_min + 1.0f), (float)WV);
        const float y_max = fminf(fmaxf(c3, y_min + 1.0f), (float)HV);

        const float sx = x_max - x_min, tx = 2.0f * x_min / (float)WV - 1.0f;
        const float sy = y_max - y_min, ty = 2.0f * y_min / (float)HV - 1.0f;

        const int oh = tid / 7;
        const int ow = tid - oh * 7;

        // x side
        const float xs = (2.0f * (float)ow + 1.0f) / (float)OUT_W - 1.0f;
        const float gx = sx * xs + tx;
        const float px = ((gx + 1.0f) * (float)WV - 1.0f) * 0.5f;
        const float x0f = floorf(px);
        const float wx1 = px - x0f, wx0 = 1.0f - wx1;
        const int x0i = (int)x0f, x1i = x0i + 1;
        const float vx0 = (x0i >= 0 && x0i < WV) ? 1.0f : 0.0f;
        const float vx1 = (x1i >= 0 && x1i < WV) ? 1.0f : 0.0f;
        const int xc0 = min(max(x0i, 0), WV - 1);
        const int xc1 = min(max(x1i, 0), WV - 1);

        // y side
        const float ys = (2.0f * (float)oh + 1.0f) / (float)OUT_H - 1.0f;
        const float gy = sy * ys + ty;
        const float py = ((gy + 1.0f) * (float)HV - 1.0f) * 0.5f;
        const float y0f = floorf(py);
        const float wy1 = py - y0f, wy0 = 1.0f - wy1;
        const int y0i = (int)y0f, y1i = y0i + 1;
        const float vy0 = (y0i >= 0 && y0i < HV) ? 1.0f : 0.0f;
        const float vy1 = (y1i >= 0 && y1i < HV) ? 1.0f : 0.0f;
        const int yc0 = min(max(y0i, 0), HV - 1);
        const int yc1 = min(max(y1i, 0), HV - 1);

        // combined linear offsets + combined weights
        s_o00[tid] = yc0 * WV + xc0;
        s_o01[tid] = yc0 * WV + xc1;
        s_o10[tid] = yc1 * WV + xc0;
        s_o11[tid] = yc1 * WV + xc1;
        const float a0 = wy0 * vy0, a1 = wy1 * vy1;
        const float b0 = wx0 * vx0, b1 = wx1 * vx1;
        s_w00[tid] = a0 * b0;
        s_w01[tid] = a0 * b1;
        s_w10[tid] = a1 * b0;
        s_w11[tid] = a1 * b1;
    }
    __syncthreads();

    const int b = s_b;
    const float* __restrict__ base = fm + ((size_t)b * CV + (size_t)q * CPB) * (HV * WV);
    float* __restrict__ outn = out + ((size_t)n * CV + (size_t)q * CPB) * 49;

    #pragma unroll 4
    for (int e = tid; e < EPB; e += 256) {
        const int c = e / 49;
        const int p = e - c * 49;
        const float* __restrict__ bc = base + c * (HV * WV);
        const int o00 = s_o00[p], o01 = s_o01[p], o10 = s_o10[p], o11 = s_o11[p];
        const float w00 = s_w00[p], w01 = s_w01[p], w10 = s_w10[p], w11 = s_w11[p];
        const float a00 = bc[o00];
        const float a01 = bc[o01];
        const float a10 = bc[o10];
        const float a11 = bc[o11];
        float v = w00 * a00;
        v = fmaf(w01, a01, v);
        v = fmaf(w10, a10, v);
        v = fmaf(w11, a11, v);
        __builtin_nontemporal_store(v, &outn[e]);
    }
}

extern "C" void kernel_launch(void* const* d_in, const int* in_sizes, int n_in,
                              void* d_out, int out_size, void* d_ws, size_t ws_size,
                              hipStream_t stream) {
    const float* fm = (const float*)d_in[0];
    const float* rois = (const float*)d_in[1];
    float* out = (float*)d_out;
    const int N = in_sizes[1] / 5;  // 1000 rois
    roi_align_kernel<<<dim3(N, CV / CPB), dim3(256), 0, stream>>>(fm, rois, out);
}

// Round 4
// 38.416 us; speedup vs baseline: 1.4083x; 1.2763x over previous
//
#include <hip/hip_runtime.h>

#define SCALE 0.25f
#define OUT_H 7
#define OUT_W 7
#define CV 256
#define HV 200
#define WV 200
#define CPB 64              // channels per block (gridDim.y = CV/CPB)
#define EPB (CPB * 49)      // elements per block = 3136

// two adjacent floats, natural alignment 4 — lets clang merge into one
// (unaligned-capable) global_load_dwordx2 on gfx950
struct f2u { float x, y; };

__global__ __launch_bounds__(256) void roi_align_kernel(
    const float* __restrict__ fm, const float* __restrict__ rois,
    float* __restrict__ out)
{
    __shared__ int s_b;
    __shared__ int2   s_o[49];   // linear offsets of (row0,xb) and (row1,xb)
    __shared__ float4 s_q[49];   // weights for {r0.x, r0.y, r1.x, r1.y}

    const int n = blockIdx.x;
    const int q = blockIdx.y;    // channel quarter
    const int tid = threadIdx.x;

    if (tid < 49) {
        const float r0 = rois[n * 5 + 0] * SCALE;
        const float r1 = rois[n * 5 + 1] * SCALE;
        const float r2 = rois[n * 5 + 2] * SCALE;
        const float r3 = rois[n * 5 + 3] * SCALE;
        if (tid == 0) s_b = (int)(rois[n * 5 + 4] * SCALE);  // faithful quirk

        const float c0 = r0 * SCALE, c1 = r1 * SCALE;        // second scale (faithful)
        const float c2 = r2 * SCALE, c3 = r3 * SCALE;

        const float x_min = fminf(fmaxf(c0, 0.0f), (float)(WV - 1));
        const float y_min = fminf(fmaxf(c1, 0.0f), (float)(HV - 1));
        const float x_max = fminf(fmaxf(c2, x_min + 1.0f), (float)WV);
        const float y_max = fminf(fmaxf(c3, y_min + 1.0f), (float)HV);

        const float sx = x_max - x_min, tx = 2.0f * x_min / (float)WV - 1.0f;
        const float sy = y_max - y_min, ty = 2.0f * y_min / (float)HV - 1.0f;

        const int oh = tid / 7;
        const int ow = tid - oh * 7;

        // ---- x side: merged adjacent pair {x0, x0+1} at base column xb ----
        const float xs = (2.0f * (float)ow + 1.0f) / (float)OUT_W - 1.0f;
        const float gx = sx * xs + tx;
        const float px = ((gx + 1.0f) * (float)WV - 1.0f) * 0.5f;
        const float x0f = floorf(px);
        const float wx1 = px - x0f, wx0 = 1.0f - wx1;
        const int x0i = (int)x0f, x1i = x0i + 1;
        const bool vx0 = (x0i >= 0 && x0i < WV);
        const bool vx1 = (x1i >= 0 && x1i < WV);
        const int xb = min(max(x0i, 0), WV - 2);
        // weight of element at column xb / xb+1 (0 if that corner invalid or not mapped)
        const float wA = (vx0 && x0i == xb)     ? wx0 : ((vx1 && x1i == xb)     ? wx1 : 0.0f);
        const float wB = (vx1 && x1i == xb + 1) ? wx1 : ((vx0 && x0i == xb + 1) ? wx0 : 0.0f);

        // ---- y side: two independent rows ----
        const float ys = (2.0f * (float)oh + 1.0f) / (float)OUT_H - 1.0f;
        const float gy = sy * ys + ty;
        const float py = ((gy + 1.0f) * (float)HV - 1.0f) * 0.5f;
        const float y0f = floorf(py);
        const float wy1 = py - y0f, wy0 = 1.0f - wy1;
        const int y0i = (int)y0f, y1i = y0i + 1;
        const float wyA = (y0i >= 0 && y0i < HV) ? wy0 : 0.0f;
        const float wyB = (y1i >= 0 && y1i < HV) ? wy1 : 0.0f;
        const int yc0 = min(max(y0i, 0), HV - 1);
        const int yc1 = min(max(y1i, 0), HV - 1);

        s_o[tid] = make_int2(yc0 * WV + xb, yc1 * WV + xb);
        s_q[tid] = make_float4(wyA * wA, wyA * wB, wyB * wA, wyB * wB);
    }
    __syncthreads();

    const int b = s_b;
    const float* __restrict__ base = fm + ((size_t)b * CV + (size_t)q * CPB) * (HV * WV);
    float* __restrict__ outn = out + ((size_t)n * CV + (size_t)q * CPB) * 49;

    #pragma unroll 4
    for (int e = tid; e < EPB; e += 256) {
        const int c = e / 49;
        const int p = e - c * 49;
        const float* __restrict__ bc = base + c * (HV * WV);
        const int2 o = s_o[p];
        const float4 w = s_q[p];
        const f2u r0 = *reinterpret_cast<const f2u*>(bc + o.x);
        const f2u r1 = *reinterpret_cast<const f2u*>(bc + o.y);
        float v = w.x * r0.x;
        v = fmaf(w.y, r0.y, v);
        v = fmaf(w.z, r1.x, v);
        v = fmaf(w.w, r1.y, v);
        __builtin_nontemporal_store(v, &outn[e]);
    }
}

extern "C" void kernel_launch(void* const* d_in, const int* in_sizes, int n_in,
                              void* d_out, int out_size, void* d_ws, size_t ws_size,
                              hipStream_t stream) {
    const float* fm = (const float*)d_in[0];
    const float* rois = (const float*)d_in[1];
    float* out = (float*)d_out;
    const int N = in_sizes[1] / 5;  // 1000 rois
    roi_align_kernel<<<dim3(N, CV / CPB), dim3(256), 0, stream>>>(fm, rois, out);
}

// Round 5
// 37.703 us; speedup vs baseline: 1.4349x; 1.0189x over previous
//
#include <hip/hip_runtime.h>

#define SCALE 0.25f
#define OUT_H 7
#define OUT_W 7
#define CV 256
#define HV 200
#define WV 200
#define CPB 64               // channels per block (gridDim.y = CV/CPB)
#define EPB (CPB * 49)       // 3136 elements per block
#define TPB 448              // 7 waves; 3136 = 448 * 7 exactly
#define ITERS 7

struct f2u { float x, y; };

__global__ __launch_bounds__(TPB) void roi_align_kernel(
    const float* __restrict__ fm, const float* __restrict__ rois,
    float* __restrict__ out)
{
    __shared__ int s_b;
    __shared__ int2   s_o[49];   // linear offsets of (row0,xb), (row1,xb)
    __shared__ float4 s_q[49];   // weights for {r0.x, r0.y, r1.x, r1.y}

    const int n = blockIdx.x;
    const int q = blockIdx.y;
    const int tid = threadIdx.x;

    if (tid < 49) {
        const float r0 = rois[n * 5 + 0] * SCALE;
        const float r1 = rois[n * 5 + 1] * SCALE;
        const float r2 = rois[n * 5 + 2] * SCALE;
        const float r3 = rois[n * 5 + 3] * SCALE;
        if (tid == 0) s_b = (int)(rois[n * 5 + 4] * SCALE);  // faithful quirk

        const float c0 = r0 * SCALE, c1 = r1 * SCALE;        // second scale (faithful)
        const float c2 = r2 * SCALE, c3 = r3 * SCALE;

        const float x_min = fminf(fmaxf(c0, 0.0f), (float)(WV - 1));
        const float y_min = fminf(fmaxf(c1, 0.0f), (float)(HV - 1));
        const float x_max = fminf(fmaxf(c2, x_min + 1.0f), (float)WV);
        const float y_max = fminf(fmaxf(c3, y_min + 1.0f), (float)HV);

        const float sx = x_max - x_min, tx = 2.0f * x_min / (float)WV - 1.0f;
        const float sy = y_max - y_min, ty = 2.0f * y_min / (float)HV - 1.0f;

        const int oh = tid / 7;
        const int ow = tid - oh * 7;

        // x side: merged adjacent pair {x0, x0+1} based at column xb in [0, W-2]
        const float xs = (2.0f * (float)ow + 1.0f) / (float)OUT_W - 1.0f;
        const float gx = sx * xs + tx;
        const float px = ((gx + 1.0f) * (float)WV - 1.0f) * 0.5f;
        const float x0f = floorf(px);
        const float wx1 = px - x0f, wx0 = 1.0f - wx1;
        const int x0i = (int)x0f, x1i = x0i + 1;
        const bool vx0 = (x0i >= 0 && x0i < WV);
        const bool vx1 = (x1i >= 0 && x1i < WV);
        const int xb = min(max(x0i, 0), WV - 2);
        const float wA = (vx0 && x0i == xb)     ? wx0 : ((vx1 && x1i == xb)     ? wx1 : 0.0f);
        const float wB = (vx1 && x1i == xb + 1) ? wx1 : ((vx0 && x0i == xb + 1) ? wx0 : 0.0f);

        // y side
        const float ys = (2.0f * (float)oh + 1.0f) / (float)OUT_H - 1.0f;
        const float gy = sy * ys + ty;
        const float py = ((gy + 1.0f) * (float)HV - 1.0f) * 0.5f;
        const float y0f = floorf(py);
        const float wy1 = py - y0f, wy0 = 1.0f - wy1;
        const int y0i = (int)y0f, y1i = y0i + 1;
        const float wyA = (y0i >= 0 && y0i < HV) ? wy0 : 0.0f;
        const float wyB = (y1i >= 0 && y1i < HV) ? wy1 : 0.0f;
        const int yc0 = min(max(y0i, 0), HV - 1);
        const int yc1 = min(max(y1i, 0), HV - 1);

        s_o[tid] = make_int2(yc0 * WV + xb, yc1 * WV + xb);
        s_q[tid] = make_float4(wyA * wA, wyA * wB, wyB * wA, wyB * wB);
    }
    __syncthreads();

    const int b = s_b;
    const float* __restrict__ base = fm + ((size_t)b * CV + (size_t)q * CPB) * (HV * WV);
    float* __restrict__ outn = out + ((size_t)n * CV + (size_t)q * CPB) * 49;

    // thread tid owns elements e_k = tid + k*448, k=0..6 (exact cover of 3136)
    // incremental (c,p): stride 448 = 9*49 + 7
    int c = tid / 49;
    int p = tid - c * 49;

    f2u   r0s[ITERS], r1s[ITERS];
    float4 ws[ITERS];
    int   cs[ITERS];

    // phase 1: compute addresses, issue ALL 14 gather loads (max MLP)
    #pragma unroll
    for (int k = 0; k < ITERS; ++k) {
        const int2 o = s_o[p];
        ws[k] = s_q[p];
        cs[k] = c;
        const float* __restrict__ bc = base + c * (HV * WV);
        r0s[k] = *reinterpret_cast<const f2u*>(bc + o.x);
        r1s[k] = *reinterpret_cast<const f2u*>(bc + o.y);
        // advance e by 448: p += 7 (mod 49), c += 9 (+1 on wrap)
        const int p2 = p + 7;
        const bool wrap = p2 >= 49;
        p = wrap ? p2 - 49 : p2;
        c += wrap ? 10 : 9;
    }

    // phase 2: consume + store
    #pragma unroll
    for (int k = 0; k < ITERS; ++k) {
        const float4 w = ws[k];
        float v = w.x * r0s[k].x;
        v = fmaf(w.y, r0s[k].y, v);
        v = fmaf(w.z, r1s[k].x, v);
        v = fmaf(w.w, r1s[k].y, v);
        __builtin_nontemporal_store(v, &outn[tid + k * TPB]);
    }
}

extern "C" void kernel_launch(void* const* d_in, const int* in_sizes, int n_in,
                              void* d_out, int out_size, void* d_ws, size_t ws_size,
                              hipStream_t stream) {
    const float* fm = (const float*)d_in[0];
    const float* rois = (const float*)d_in[1];
    float* out = (float*)d_out;
    const int N = in_sizes[1] / 5;  // 1000 rois
    roi_align_kernel<<<dim3(N, CV / CPB), dim3(TPB), 0, stream>>>(fm, rois, out);
}